// Round 1
// baseline (1772.598 us; speedup 1.0000x reference)
//
#include <hip/hip_runtime.h>
#include <hip/hip_bf16.h>
#include <cstdint>
#include <cstddef>

#define H 512
#define NFEAT 1024
#define BATCH 16384

using bf16 = __hip_bfloat16;
using bf16x8 = __attribute__((ext_vector_type(8))) __bf16;
using f32x4 = __attribute__((ext_vector_type(4))) float;

// ---------------------------------------------------------------------------
// async global -> LDS, 16 bytes per lane
// ---------------------------------------------------------------------------
__device__ __forceinline__ void gload16(void* lds, const void* g) {
  __builtin_amdgcn_global_load_lds(
      (__attribute__((address_space(1))) void*)g,
      (__attribute__((address_space(3))) void*)lds,
      16, 0, 0);
}

// ---------------------------------------------------------------------------
// prep: per matrix, compute a[], b[] for core = diag(d) + a*1^T + b*u^T
// Closed-form Cayley: S = u 1^T - 1 u^T (rank 2) ->
//   R = I + c_uv u 1^T + c_uu u u^T + c_vv 1 1^T + c_vu 1 u^T
//   c_uv=2(1+s)/det, c_uu=-2H/det, c_vv=-2q/det, c_vu=-2(1-s)/det
//   det = 1 - s^2 + H q,  s=sum(u), q=sum(u^2)
// ---------------------------------------------------------------------------
__global__ void prep_kernel(const float* __restrict__ er, const float* __restrict__ ed,
                            const float* __restrict__ dr, const float* __restrict__ dd,
                            float* __restrict__ ab) {
  const int mat = blockIdx.x;          // 0..7
  const int lane = threadIdx.x;        // 0..63
  const float* u = (mat < 4) ? (er + mat * H) : (dr + (mat - 4) * H);
  const float* d = (mat < 4) ? (ed + mat * H) : (dd + (mat - 4) * H);

  double s = 0.0, q = 0.0;
  for (int k = 0; k < 8; ++k) {
    double v = (double)u[lane + 64 * k];
    s += v;
    q += v * v;
  }
  for (int off = 32; off; off >>= 1) {
    s += __shfl_down(s, off);
    q += __shfl_down(q, off);
  }
  s = __shfl(s, 0);
  q = __shfl(q, 0);

  const double det = 1.0 - s * s + (double)H * q;
  const double cuv = 2.0 * (1.0 + s) / det;
  const double cuu = -2.0 * (double)H / det;
  const double cvv = -2.0 * q / det;
  const double cvu = -2.0 * (1.0 - s) / det;

  float* a = ab + mat * 1024;
  float* b = a + H;
  for (int k = 0; k < 8; ++k) {
    int idx = lane + 64 * k;
    double ui = (double)u[idx], di = (double)d[idx];
    a[idx] = (float)(di * (cuv * ui + cvv));
    b[idx] = (float)(di * (cuu * ui + cvu));
  }
}

// ---------------------------------------------------------------------------
// build: L[i][j] = sum over offsets o in [lo,hi] of rots[o%4][i-o][j-o]
//   rots0[p][q] = d[p]*(p==q)          + a[p]       + b[p]      *u[q]
//   rots1[p][q] = d[q]*(q==511-p)      + a[q]       + b[q]      *u[511-p]
//   rots2[p][q] = d[511-p]*(p==q)      + a[511-p]   + b[511-p]  *u[511-q]
//   rots3[p][q] = d[511-q]*(p==511-q)  + a[511-q]   + b[511-q]  *u[p]
// Write L split into hi/lo bf16.
// ---------------------------------------------------------------------------
__global__ __launch_bounds__(256) void build_kernel(
    const float* __restrict__ er, const float* __restrict__ ed,
    const float* __restrict__ dr, const float* __restrict__ dd,
    const float* __restrict__ ab, bf16* __restrict__ Lh, bf16* __restrict__ Ll) {
  const int j = blockIdx.x * 256 + threadIdx.x;
  const int i = blockIdx.y;
  const int mat = blockIdx.z;
  const float* u = (mat < 4) ? (er + mat * H) : (dr + (mat - 4) * H);
  const float* d = (mat < 4) ? (ed + mat * H) : (dd + (mat - 4) * H);
  const float* a = ab + mat * 1024;
  const float* b = a + H;

  const int lo = max(0, max(i, j) - (H - 1));
  const int hi = min(H, min(i, j));
  float v = 0.f;
  if (lo <= hi) {
    const bool dg = (i == j);
    for (int o = lo + ((0 - lo) & 3); o <= hi; o += 4) {       // o % 4 == 0
      int p = i - o, q = j - o;
      float t = a[p] + b[p] * u[q];
      if (dg) t += d[p];
      v += t;
    }
    for (int o = lo + ((1 - lo) & 3); o <= hi; o += 4) {       // o % 4 == 1
      int p = i - o, q = j - o;
      v += a[q] + b[q] * u[511 - p];
    }
    for (int o = lo + ((2 - lo) & 3); o <= hi; o += 4) {       // o % 4 == 2
      int p = i - o, q = j - o;
      float t = a[511 - p] + b[511 - p] * u[511 - q];
      if (dg) t += d[511 - p];
      v += t;
    }
    for (int o = lo + ((3 - lo) & 3); o <= hi; o += 4) {       // o % 4 == 3
      int p = i - o, q = j - o;
      v += a[511 - q] + b[511 - q] * u[p];
    }
    // anti-diagonal delta terms (rots1 / rots3): 2o == i + j - 511
    const int m2 = i + j - 511;
    if (m2 >= 0 && (m2 & 1) == 0) {
      int o = m2 >> 1;
      if (o >= lo && o <= hi) {
        if ((o & 3) == 1)      v += d[j - o];
        else if ((o & 3) == 3) v += d[511 - (j - o)];
      }
    }
  }
  const size_t off = ((size_t)mat << 20) + ((size_t)i << 10) + (size_t)j;
  bf16 hb = __float2bfloat16(v);
  Lh[off] = hb;
  Ll[off] = __float2bfloat16(v - __bfloat162float(hb));
}

// ---------------------------------------------------------------------------
// split fp32 -> (hi, lo) bf16
// ---------------------------------------------------------------------------
__global__ void split_kernel(const float* __restrict__ x, bf16* __restrict__ h,
                             bf16* __restrict__ l) {
  const int n4 = BATCH * NFEAT / 4;
  int idx = blockIdx.x * blockDim.x + threadIdx.x;
  int stride = gridDim.x * blockDim.x;
  for (int i = idx; i < n4; i += stride) {
    float4 v = ((const float4*)x)[i];
    float vv[4] = {v.x, v.y, v.z, v.w};
    union { bf16 b[4]; short4 s; } Hu, Lu;
#pragma unroll
    for (int c = 0; c < 4; ++c) {
      bf16 hb = __float2bfloat16(vv[c]);
      Hu.b[c] = hb;
      Lu.b[c] = __float2bfloat16(vv[c] - __bfloat162float(hb));
    }
    ((short4*)h)[i] = Hu.s;
    ((short4*)l)[i] = Lu.s;
  }
}

// ---------------------------------------------------------------------------
// split-bf16 GEMM:  Y[r][c] = sum_k S[r][k] * L[c][k]   (i.e. Y = S @ L^T)
// with S ~ Ah+Al, L ~ Bh+Bl; acc += Ah*Bh + Ah*Bl + Al*Bh  (fp32 accum)
// 128x128 tile, BK=32, 4 waves (2x2), mfma_f32_16x16x32_bf16.
// MODE bit0: write fp32 Yf; bit1: write split (Yh, Yl)
// ---------------------------------------------------------------------------
template <int MODE>
__global__ __launch_bounds__(256) void gemm3_kernel(
    const bf16* __restrict__ Ah, const bf16* __restrict__ Al,
    const bf16* __restrict__ Bh, const bf16* __restrict__ Bl,
    float* __restrict__ Yf, bf16* __restrict__ Yh, bf16* __restrict__ Yl) {
  __shared__ __align__(16) bf16 sAh[128 * 32];
  __shared__ __align__(16) bf16 sAl[128 * 32];
  __shared__ __align__(16) bf16 sBh[128 * 32];
  __shared__ __align__(16) bf16 sBl[128 * 32];

  const int tid = threadIdx.x;
  const int lane = tid & 63;
  const int wave = tid >> 6;
  const int wr = wave >> 1;  // 0..1
  const int wc = wave & 1;   // 0..1
  const int row0 = blockIdx.x * 128;  // batch rows (fast-varying for L2 reuse of B)
  const int col0 = blockIdx.y * 128;  // output features

  // staging addressing: thread covers 16B; row = tid>>2, kpart = tid&3
  const int srow = tid >> 2;
  const int kq = tid & 3;
  const size_t aoff0 = (size_t)(row0 + srow) * NFEAT + (size_t)kq * 8;
  const size_t aoff1 = aoff0 + (size_t)64 * NFEAT;
  const size_t boff0 = (size_t)(col0 + srow) * NFEAT + (size_t)kq * 8;
  const size_t boff1 = boff0 + (size_t)64 * NFEAT;
  const int ldst = tid * 8;  // element offset in LDS tile (== srow*32 + kq*8)

  f32x4 acc[4][4] = {};

  for (int k0 = 0; k0 < NFEAT; k0 += 32) {
    gload16(sAh + ldst,        Ah + aoff0 + k0);
    gload16(sAh + 2048 + ldst, Ah + aoff1 + k0);
    gload16(sAl + ldst,        Al + aoff0 + k0);
    gload16(sAl + 2048 + ldst, Al + aoff1 + k0);
    gload16(sBh + ldst,        Bh + boff0 + k0);
    gload16(sBh + 2048 + ldst, Bh + boff1 + k0);
    gload16(sBl + ldst,        Bl + boff0 + k0);
    gload16(sBl + 2048 + ldst, Bl + boff1 + k0);
    __syncthreads();

    const int r16 = lane & 15;
    const int kg = (lane >> 4) * 8;
    bf16x8 fah[4], fal[4], fbh[4], fbl[4];
#pragma unroll
    for (int m = 0; m < 4; ++m) {
      int ra = (wr * 64 + m * 16 + r16) * 32 + kg;
      fah[m] = *(const bf16x8*)(sAh + ra);
      fal[m] = *(const bf16x8*)(sAl + ra);
      int rb = (wc * 64 + m * 16 + r16) * 32 + kg;
      fbh[m] = *(const bf16x8*)(sBh + rb);
      fbl[m] = *(const bf16x8*)(sBl + rb);
    }
#pragma unroll
    for (int m = 0; m < 4; ++m)
#pragma unroll
      for (int n = 0; n < 4; ++n) {
        acc[m][n] = __builtin_amdgcn_mfma_f32_16x16x32_bf16(fah[m], fbh[n], acc[m][n], 0, 0, 0);
        acc[m][n] = __builtin_amdgcn_mfma_f32_16x16x32_bf16(fah[m], fbl[n], acc[m][n], 0, 0, 0);
        acc[m][n] = __builtin_amdgcn_mfma_f32_16x16x32_bf16(fal[m], fbh[n], acc[m][n], 0, 0, 0);
      }
    __syncthreads();
  }

  // epilogue: C/D layout (16x16x32): col = lane&15, row = (lane>>4)*4 + reg
  const int orow = wr * 64 + ((lane >> 4) << 2);
  const int ocol = wc * 64 + (lane & 15);
#pragma unroll
  for (int m = 0; m < 4; ++m)
#pragma unroll
    for (int n = 0; n < 4; ++n)
#pragma unroll
      for (int r = 0; r < 4; ++r) {
        const int grow = row0 + orow + m * 16 + r;
        const int gcol = col0 + ocol + n * 16;
        const size_t off = (size_t)grow * NFEAT + (size_t)gcol;
        const float v = acc[m][n][r];
        if (MODE & 1) Yf[off] = v;
        if (MODE & 2) {
          bf16 hb = __float2bfloat16(v);
          Yh[off] = hb;
          Yl[off] = __float2bfloat16(v - __bfloat162float(hb));
        }
      }
}

// ---------------------------------------------------------------------------
// launch
// ---------------------------------------------------------------------------
extern "C" void kernel_launch(void* const* d_in, const int* in_sizes, int n_in,
                              void* d_out, int out_size, void* d_ws, size_t ws_size,
                              hipStream_t stream) {
  (void)in_sizes; (void)n_in; (void)out_size; (void)ws_size;
  const float* x  = (const float*)d_in[0];
  const float* er = (const float*)d_in[1];
  const float* ed = (const float*)d_in[2];
  const float* dr = (const float*)d_in[3];
  const float* dd = (const float*)d_in[4];

  float* O0 = (float*)d_out;                       // bottleneck (fp32, 64 MB)
  float* O1 = O0 + (size_t)BATCH * NFEAT;          // out (fp32, 64 MB)

  // d_ws layout: Lh (16MB) | Ll (16MB) | ab (32KB) | Ph (32MB) | Pl (32MB)
  bf16* Lh = (bf16*)d_ws;
  bf16* Ll = Lh + ((size_t)8 << 20);
  float* ab = (float*)(Ll + ((size_t)8 << 20));
  bf16* Ph = (bf16*)(ab + 8 * 1024);
  bf16* Pl = Ph + (size_t)BATCH * NFEAT;
  // d_out second half doubles as bf16 hi/lo ping buffer until layer 8 overwrites it
  bf16* Qh = (bf16*)O1;
  bf16* Ql = Qh + (size_t)BATCH * NFEAT;

  prep_kernel<<<8, 64, 0, stream>>>(er, ed, dr, dd, ab);
  build_kernel<<<dim3(4, 1024, 8), 256, 0, stream>>>(er, ed, dr, dd, ab, Lh, Ll);
  split_kernel<<<4096, 256, 0, stream>>>(x, Qh, Ql);

  const dim3 g(128, 8);
  const size_t LM = (size_t)1 << 20;
  // encoder
  gemm3_kernel<2><<<g, 256, 0, stream>>>(Qh, Ql, Lh + 0 * LM, Ll + 0 * LM, nullptr, Ph, Pl);
  gemm3_kernel<2><<<g, 256, 0, stream>>>(Ph, Pl, Lh + 1 * LM, Ll + 1 * LM, nullptr, Qh, Ql);
  gemm3_kernel<2><<<g, 256, 0, stream>>>(Qh, Ql, Lh + 2 * LM, Ll + 2 * LM, nullptr, Ph, Pl);
  gemm3_kernel<3><<<g, 256, 0, stream>>>(Ph, Pl, Lh + 3 * LM, Ll + 3 * LM, O0, Qh, Ql);
  // decoder
  gemm3_kernel<2><<<g, 256, 0, stream>>>(Qh, Ql, Lh + 4 * LM, Ll + 4 * LM, nullptr, Ph, Pl);
  gemm3_kernel<2><<<g, 256, 0, stream>>>(Ph, Pl, Lh + 5 * LM, Ll + 5 * LM, nullptr, Qh, Ql);
  gemm3_kernel<2><<<g, 256, 0, stream>>>(Qh, Ql, Lh + 6 * LM, Ll + 6 * LM, nullptr, Ph, Pl);
  gemm3_kernel<1><<<g, 256, 0, stream>>>(Ph, Pl, Lh + 7 * LM, Ll + 7 * LM, O1, nullptr, nullptr);
}

// Round 2
// 1217.874 us; speedup vs baseline: 1.4555x; 1.4555x over previous
//
#include <hip/hip_runtime.h>
#include <hip/hip_bf16.h>
#include <cstdint>
#include <cstddef>

#define H 512
#define NFEAT 1024
#define BATCH 16384

using bf16 = __hip_bfloat16;
using bf16x8 = __attribute__((ext_vector_type(8))) __bf16;
using f32x4 = __attribute__((ext_vector_type(4))) float;

// ---------------------------------------------------------------------------
// async global -> LDS, 16 bytes per lane
// ---------------------------------------------------------------------------
__device__ __forceinline__ void gload16(void* lds, const void* g) {
  __builtin_amdgcn_global_load_lds(
      (__attribute__((address_space(1))) void*)g,
      (__attribute__((address_space(3))) void*)lds,
      16, 0, 0);
}

// ---------------------------------------------------------------------------
// prep: per matrix, compute a[], b[] for core = diag(d) + a*1^T + b*u^T
// Closed-form Cayley: S = u 1^T - 1 u^T (rank 2) ->
//   R = I + c_uv u 1^T + c_uu u u^T + c_vv 1 1^T + c_vu 1 u^T
//   c_uv=2(1+s)/det, c_uu=-2H/det, c_vv=-2q/det, c_vu=-2(1-s)/det
//   det = 1 - s^2 + H q,  s=sum(u), q=sum(u^2)
// ---------------------------------------------------------------------------
__global__ void prep_kernel(const float* __restrict__ er, const float* __restrict__ ed,
                            const float* __restrict__ dr, const float* __restrict__ dd,
                            float* __restrict__ ab) {
  const int mat = blockIdx.x;          // 0..7
  const int lane = threadIdx.x;        // 0..63
  const float* u = (mat < 4) ? (er + mat * H) : (dr + (mat - 4) * H);
  const float* d = (mat < 4) ? (ed + mat * H) : (dd + (mat - 4) * H);

  double s = 0.0, q = 0.0;
  for (int k = 0; k < 8; ++k) {
    double v = (double)u[lane + 64 * k];
    s += v;
    q += v * v;
  }
  for (int off = 32; off; off >>= 1) {
    s += __shfl_down(s, off);
    q += __shfl_down(q, off);
  }
  s = __shfl(s, 0);
  q = __shfl(q, 0);

  const double det = 1.0 - s * s + (double)H * q;
  const double cuv = 2.0 * (1.0 + s) / det;
  const double cuu = -2.0 * (double)H / det;
  const double cvv = -2.0 * q / det;
  const double cvu = -2.0 * (1.0 - s) / det;

  float* a = ab + mat * 1024;
  float* b = a + H;
  for (int k = 0; k < 8; ++k) {
    int idx = lane + 64 * k;
    double ui = (double)u[idx], di = (double)d[idx];
    a[idx] = (float)(di * (cuv * ui + cvv));
    b[idx] = (float)(di * (cuu * ui + cvu));
  }
}

// ---------------------------------------------------------------------------
// build: L[i][j] = sum over offsets o in [lo,hi] of rots[o%4][i-o][j-o]
//   rots0[p][q] = d[p]*(p==q)          + a[p]       + b[p]      *u[q]
//   rots1[p][q] = d[q]*(q==511-p)      + a[q]       + b[q]      *u[511-p]
//   rots2[p][q] = d[511-p]*(p==q)      + a[511-p]   + b[511-p]  *u[511-q]
//   rots3[p][q] = d[511-q]*(p==511-q)  + a[511-q]   + b[511-q]  *u[p]
// v2: LDS-staged a/b/u/d (uniform reads broadcast, lane reads stride +-1,
// conflict-free), diagonal term hoisted out of hot loop, 2-way unrolled
// independent accumulators. Write L split into hi/lo bf16.
// ---------------------------------------------------------------------------
__global__ __launch_bounds__(256) void build_kernel(
    const float* __restrict__ er, const float* __restrict__ ed,
    const float* __restrict__ dr, const float* __restrict__ dd,
    const float* __restrict__ ab, bf16* __restrict__ Lh, bf16* __restrict__ Ll) {
  __shared__ float sa[512], sb[512], su[512], sd[512];
  const int mat = blockIdx.z;
  const float* u = (mat < 4) ? (er + mat * H) : (dr + (mat - 4) * H);
  const float* d = (mat < 4) ? (ed + mat * H) : (dd + (mat - 4) * H);
  const float* a = ab + mat * 1024;
  const float* b = a + H;
  for (int k = threadIdx.x; k < H; k += 256) {
    sa[k] = a[k];
    sb[k] = b[k];
    su[k] = u[k];
    sd[k] = d[k];
  }
  __syncthreads();

  const int j = blockIdx.x * 256 + threadIdx.x;
  const int i = blockIdx.y;

  const int lo = max(0, max(i, j) - (H - 1));
  const int hi = min(H, min(i, j));
  float v = 0.f;
  if (lo <= hi) {
    // form 0: o % 4 == 0   term = a[p] + b[p]*u[q]   (a,b uniform; u lane-stride)
    {
      int o = lo + ((0 - lo) & 3);
      float t0 = 0.f, t1 = 0.f;
      for (; o + 4 <= hi; o += 8) {
        t0 += sa[i - o] + sb[i - o] * su[j - o];
        t1 += sa[i - o - 4] + sb[i - o - 4] * su[j - o - 4];
      }
      if (o <= hi) t0 += sa[i - o] + sb[i - o] * su[j - o];
      v += t0 + t1;
    }
    // form 1: o % 4 == 1   term = a[q] + b[q]*u[511-p]   (u uniform; a,b lane-stride)
    {
      int o = lo + ((1 - lo) & 3);
      float t0 = 0.f, t1 = 0.f;
      for (; o + 4 <= hi; o += 8) {
        t0 += sa[j - o] + sb[j - o] * su[511 - i + o];
        t1 += sa[j - o - 4] + sb[j - o - 4] * su[511 - i + o + 4];
      }
      if (o <= hi) t0 += sa[j - o] + sb[j - o] * su[511 - i + o];
      v += t0 + t1;
    }
    // form 2: o % 4 == 2   term = a[511-p] + b[511-p]*u[511-q]
    {
      int o = lo + ((2 - lo) & 3);
      float t0 = 0.f, t1 = 0.f;
      for (; o + 4 <= hi; o += 8) {
        t0 += sa[511 - i + o] + sb[511 - i + o] * su[511 - j + o];
        t1 += sa[511 - i + o + 4] + sb[511 - i + o + 4] * su[511 - j + o + 4];
      }
      if (o <= hi) t0 += sa[511 - i + o] + sb[511 - i + o] * su[511 - j + o];
      v += t0 + t1;
    }
    // form 3: o % 4 == 3   term = a[511-q] + b[511-q]*u[p]
    {
      int o = lo + ((3 - lo) & 3);
      float t0 = 0.f, t1 = 0.f;
      for (; o + 4 <= hi; o += 8) {
        t0 += sa[511 - j + o] + sb[511 - j + o] * su[i - o];
        t1 += sa[511 - j + o + 4] + sb[511 - j + o + 4] * su[i - o - 4];
      }
      if (o <= hi) t0 += sa[511 - j + o] + sb[511 - j + o] * su[i - o];
      v += t0 + t1;
    }
    // main-diagonal delta terms (forms 0,2), hoisted: only the i==j thread
    if (i == j) {
      for (int o = lo + ((0 - lo) & 3); o <= hi; o += 4) v += sd[i - o];
      for (int o = lo + ((2 - lo) & 3); o <= hi; o += 4) v += sd[511 - (i - o)];
    }
    // anti-diagonal delta terms (forms 1,3): 2o == i + j - 511
    const int m2 = i + j - 511;
    if (m2 >= 0 && (m2 & 1) == 0) {
      int o = m2 >> 1;
      if (o >= lo && o <= hi) {
        if ((o & 3) == 1)      v += sd[j - o];
        else if ((o & 3) == 3) v += sd[511 - (j - o)];
      }
    }
  }
  const size_t off = ((size_t)mat << 20) + ((size_t)i << 10) + (size_t)j;
  bf16 hb = __float2bfloat16(v);
  Lh[off] = hb;
  Ll[off] = __float2bfloat16(v - __bfloat162float(hb));
}

// ---------------------------------------------------------------------------
// split fp32 -> (hi, lo) bf16
// ---------------------------------------------------------------------------
__global__ void split_kernel(const float* __restrict__ x, bf16* __restrict__ h,
                             bf16* __restrict__ l) {
  const int n4 = BATCH * NFEAT / 4;
  int idx = blockIdx.x * blockDim.x + threadIdx.x;
  int stride = gridDim.x * blockDim.x;
  for (int i = idx; i < n4; i += stride) {
    float4 v = ((const float4*)x)[i];
    float vv[4] = {v.x, v.y, v.z, v.w};
    union { bf16 b[4]; short4 s; } Hu, Lu;
#pragma unroll
    for (int c = 0; c < 4; ++c) {
      bf16 hb = __float2bfloat16(vv[c]);
      Hu.b[c] = hb;
      Lu.b[c] = __float2bfloat16(vv[c] - __bfloat162float(hb));
    }
    ((short4*)h)[i] = Hu.s;
    ((short4*)l)[i] = Lu.s;
  }
}

// ---------------------------------------------------------------------------
// split-bf16 GEMM:  Y[r][c] = sum_k S[r][k] * L[c][k]   (i.e. Y = S @ L^T)
// with S ~ Ah+Al, L ~ Bh+Bl; acc += Ah*Bh + Ah*Bl + Al*Bh  (fp32 accum)
// 128x128 tile, BK=32, 4 waves (2x2), mfma_f32_16x16x32_bf16.
// MODE bit0: write fp32 Yf; bit1: write split (Yh, Yl)
// ---------------------------------------------------------------------------
template <int MODE>
__global__ __launch_bounds__(256) void gemm3_kernel(
    const bf16* __restrict__ Ah, const bf16* __restrict__ Al,
    const bf16* __restrict__ Bh, const bf16* __restrict__ Bl,
    float* __restrict__ Yf, bf16* __restrict__ Yh, bf16* __restrict__ Yl) {
  __shared__ __align__(16) bf16 sAh[128 * 32];
  __shared__ __align__(16) bf16 sAl[128 * 32];
  __shared__ __align__(16) bf16 sBh[128 * 32];
  __shared__ __align__(16) bf16 sBl[128 * 32];

  const int tid = threadIdx.x;
  const int lane = tid & 63;
  const int wave = tid >> 6;
  const int wr = wave >> 1;  // 0..1
  const int wc = wave & 1;   // 0..1
  const int row0 = blockIdx.x * 128;  // batch rows (fast-varying for L2 reuse of B)
  const int col0 = blockIdx.y * 128;  // output features

  // staging addressing: thread covers 16B; row = tid>>2, kpart = tid&3
  const int srow = tid >> 2;
  const int kq = tid & 3;
  const size_t aoff0 = (size_t)(row0 + srow) * NFEAT + (size_t)kq * 8;
  const size_t aoff1 = aoff0 + (size_t)64 * NFEAT;
  const size_t boff0 = (size_t)(col0 + srow) * NFEAT + (size_t)kq * 8;
  const size_t boff1 = boff0 + (size_t)64 * NFEAT;
  const int ldst = tid * 8;  // element offset in LDS tile (== srow*32 + kq*8)

  f32x4 acc[4][4] = {};

  for (int k0 = 0; k0 < NFEAT; k0 += 32) {
    gload16(sAh + ldst,        Ah + aoff0 + k0);
    gload16(sAh + 2048 + ldst, Ah + aoff1 + k0);
    gload16(sAl + ldst,        Al + aoff0 + k0);
    gload16(sAl + 2048 + ldst, Al + aoff1 + k0);
    gload16(sBh + ldst,        Bh + boff0 + k0);
    gload16(sBh + 2048 + ldst, Bh + boff1 + k0);
    gload16(sBl + ldst,        Bl + boff0 + k0);
    gload16(sBl + 2048 + ldst, Bl + boff1 + k0);
    __syncthreads();

    const int r16 = lane & 15;
    const int kg = (lane >> 4) * 8;
    bf16x8 fah[4], fal[4], fbh[4], fbl[4];
#pragma unroll
    for (int m = 0; m < 4; ++m) {
      int ra = (wr * 64 + m * 16 + r16) * 32 + kg;
      fah[m] = *(const bf16x8*)(sAh + ra);
      fal[m] = *(const bf16x8*)(sAl + ra);
      int rb = (wc * 64 + m * 16 + r16) * 32 + kg;
      fbh[m] = *(const bf16x8*)(sBh + rb);
      fbl[m] = *(const bf16x8*)(sBl + rb);
    }
#pragma unroll
    for (int m = 0; m < 4; ++m)
#pragma unroll
      for (int n = 0; n < 4; ++n) {
        acc[m][n] = __builtin_amdgcn_mfma_f32_16x16x32_bf16(fah[m], fbh[n], acc[m][n], 0, 0, 0);
        acc[m][n] = __builtin_amdgcn_mfma_f32_16x16x32_bf16(fah[m], fbl[n], acc[m][n], 0, 0, 0);
        acc[m][n] = __builtin_amdgcn_mfma_f32_16x16x32_bf16(fal[m], fbh[n], acc[m][n], 0, 0, 0);
      }
    __syncthreads();
  }

  // epilogue: C/D layout (16x16x32): col = lane&15, row = (lane>>4)*4 + reg
  const int orow = wr * 64 + ((lane >> 4) << 2);
  const int ocol = wc * 64 + (lane & 15);
#pragma unroll
  for (int m = 0; m < 4; ++m)
#pragma unroll
    for (int n = 0; n < 4; ++n)
#pragma unroll
      for (int r = 0; r < 4; ++r) {
        const int grow = row0 + orow + m * 16 + r;
        const int gcol = col0 + ocol + n * 16;
        const size_t off = (size_t)grow * NFEAT + (size_t)gcol;
        const float v = acc[m][n][r];
        if (MODE & 1) Yf[off] = v;
        if (MODE & 2) {
          bf16 hb = __float2bfloat16(v);
          Yh[off] = hb;
          Yl[off] = __float2bfloat16(v - __bfloat162float(hb));
        }
      }
}

// ---------------------------------------------------------------------------
// launch
// ---------------------------------------------------------------------------
extern "C" void kernel_launch(void* const* d_in, const int* in_sizes, int n_in,
                              void* d_out, int out_size, void* d_ws, size_t ws_size,
                              hipStream_t stream) {
  (void)in_sizes; (void)n_in; (void)out_size; (void)ws_size;
  const float* x  = (const float*)d_in[0];
  const float* er = (const float*)d_in[1];
  const float* ed = (const float*)d_in[2];
  const float* dr = (const float*)d_in[3];
  const float* dd = (const float*)d_in[4];

  float* O0 = (float*)d_out;                       // bottleneck (fp32, 64 MB)
  float* O1 = O0 + (size_t)BATCH * NFEAT;          // out (fp32, 64 MB)

  // d_ws layout: Lh (16MB) | Ll (16MB) | ab (32KB) | Ph (32MB) | Pl (32MB)
  bf16* Lh = (bf16*)d_ws;
  bf16* Ll = Lh + ((size_t)8 << 20);
  float* ab = (float*)(Ll + ((size_t)8 << 20));
  bf16* Ph = (bf16*)(ab + 8 * 1024);
  bf16* Pl = Ph + (size_t)BATCH * NFEAT;
  // d_out second half doubles as bf16 hi/lo ping buffer until layer 8 overwrites it
  bf16* Qh = (bf16*)O1;
  bf16* Ql = Qh + (size_t)BATCH * NFEAT;

  prep_kernel<<<8, 64, 0, stream>>>(er, ed, dr, dd, ab);
  build_kernel<<<dim3(4, 1024, 8), 256, 0, stream>>>(er, ed, dr, dd, ab, Lh, Ll);
  split_kernel<<<4096, 256, 0, stream>>>(x, Qh, Ql);

  const dim3 g(128, 8);
  const size_t LM = (size_t)1 << 20;
  // encoder
  gemm3_kernel<2><<<g, 256, 0, stream>>>(Qh, Ql, Lh + 0 * LM, Ll + 0 * LM, nullptr, Ph, Pl);
  gemm3_kernel<2><<<g, 256, 0, stream>>>(Ph, Pl, Lh + 1 * LM, Ll + 1 * LM, nullptr, Qh, Ql);
  gemm3_kernel<2><<<g, 256, 0, stream>>>(Qh, Ql, Lh + 2 * LM, Ll + 2 * LM, nullptr, Ph, Pl);
  gemm3_kernel<3><<<g, 256, 0, stream>>>(Ph, Pl, Lh + 3 * LM, Ll + 3 * LM, O0, Qh, Ql);
  // decoder
  gemm3_kernel<2><<<g, 256, 0, stream>>>(Qh, Ql, Lh + 4 * LM, Ll + 4 * LM, nullptr, Ph, Pl);
  gemm3_kernel<2><<<g, 256, 0, stream>>>(Ph, Pl, Lh + 5 * LM, Ll + 5 * LM, nullptr, Qh, Ql);
  gemm3_kernel<2><<<g, 256, 0, stream>>>(Qh, Ql, Lh + 6 * LM, Ll + 6 * LM, nullptr, Ph, Pl);
  gemm3_kernel<1><<<g, 256, 0, stream>>>(Ph, Pl, Lh + 7 * LM, Ll + 7 * LM, O1, nullptr, nullptr);
}

// Round 3
// 980.902 us; speedup vs baseline: 1.8071x; 1.2416x over previous
//
#include <hip/hip_runtime.h>
#include <hip/hip_bf16.h>
#include <cstdint>
#include <cstddef>

#define H 512
#define NFEAT 1024
#define BATCH 16384

using bf16 = __hip_bfloat16;
using bf16x8 = __attribute__((ext_vector_type(8))) __bf16;
using f32x4 = __attribute__((ext_vector_type(4))) float;

// ---------------------------------------------------------------------------
// async global -> LDS, 16 bytes per lane
// ---------------------------------------------------------------------------
__device__ __forceinline__ void gload16(void* lds, const void* g) {
  __builtin_amdgcn_global_load_lds(
      (__attribute__((address_space(1))) void*)g,
      (__attribute__((address_space(3))) void*)lds,
      16, 0, 0);
}

// ---------------------------------------------------------------------------
// prep: per matrix, compute a[], b[] for core = diag(d) + a*1^T + b*u^T
// Closed-form Cayley (rank-2 Woodbury), verified in R0/R1.
// ---------------------------------------------------------------------------
__global__ void prep_kernel(const float* __restrict__ er, const float* __restrict__ ed,
                            const float* __restrict__ dr, const float* __restrict__ dd,
                            float* __restrict__ ab) {
  const int mat = blockIdx.x;          // 0..7
  const int lane = threadIdx.x;        // 0..63
  const float* u = (mat < 4) ? (er + mat * H) : (dr + (mat - 4) * H);
  const float* d = (mat < 4) ? (ed + mat * H) : (dd + (mat - 4) * H);

  double s = 0.0, q = 0.0;
  for (int k = 0; k < 8; ++k) {
    double v = (double)u[lane + 64 * k];
    s += v;
    q += v * v;
  }
  for (int off = 32; off; off >>= 1) {
    s += __shfl_down(s, off);
    q += __shfl_down(q, off);
  }
  s = __shfl(s, 0);
  q = __shfl(q, 0);

  const double det = 1.0 - s * s + (double)H * q;
  const double cuv = 2.0 * (1.0 + s) / det;
  const double cuu = -2.0 * (double)H / det;
  const double cvv = -2.0 * q / det;
  const double cvu = -2.0 * (1.0 - s) / det;

  float* a = ab + mat * 1024;
  float* b = a + H;
  for (int k = 0; k < 8; ++k) {
    int idx = lane + 64 * k;
    double ui = (double)u[idx], di = (double)d[idx];
    a[idx] = (float)(di * (cuv * ui + cvv));
    b[idx] = (float)(di * (cuu * ui + cvu));
  }
}

// ---------------------------------------------------------------------------
// prep2: stride-4-residue inclusive prefix tables over a, a_rev, d, d_rev.
// Tpref[mat] = { pa[512], parev[512], pd[512], pdrev[512] }
//   pa[m] = sum_{m'<=m, m' == m (mod 4)} a[m']   etc.
// ---------------------------------------------------------------------------
__global__ __launch_bounds__(256) void prep2_kernel(
    const float* __restrict__ er, const float* __restrict__ ed,
    const float* __restrict__ dr, const float* __restrict__ dd,
    const float* __restrict__ ab, float* __restrict__ Tpref) {
  __shared__ float buf[4][512];
  __shared__ float tmp[4][512];
  const int mat = blockIdx.x;
  const float* d = (mat < 4) ? (ed + mat * H) : (dd + (mat - 4) * H);
  const float* a = ab + mat * 1024;
  const int t = threadIdx.x;
  for (int m = t; m < 512; m += 256) {
    buf[0][m] = a[m];
    buf[1][m] = a[511 - m];
    buf[2][m] = d[m];
    buf[3][m] = d[511 - m];
  }
  __syncthreads();
  for (int s = 4; s <= 256; s <<= 1) {
    for (int m = t; m < 512; m += 256)
#pragma unroll
      for (int q = 0; q < 4; ++q) tmp[q][m] = (m >= s) ? buf[q][m - s] : 0.f;
    __syncthreads();
    for (int m = t; m < 512; m += 256)
#pragma unroll
      for (int q = 0; q < 4; ++q) buf[q][m] += tmp[q][m];
    __syncthreads();
  }
  float* tp = Tpref + mat * 2048;
  for (int m = t; m < 512; m += 256) {
    tp[m] = buf[0][m];
    tp[512 + m] = buf[1][m];
    tp[1024 + m] = buf[2][m];
    tp[1536 + m] = buf[3][m];
  }
}

// ---------------------------------------------------------------------------
// build v3: L[i][j] = sum over o in [lo,hi] of rots[o%4][i-o][j-o]
//   rots0[p][q] = d[p](p==q)     + a[p]     + b[p]    *u[q]
//   rots1[p][q] = d[q](q==511-p) + a[q]     + b[q]    *u[511-p]
//   rots2[p][q] = d[511-p](p==q) + a[511-p] + b[511-p]*u[511-q]
//   rots3[p][q] = d[511-q](p==511-q) + a[511-q] + b[511-q]*u[p]
// a/d-parts via prefix tables (O(1) per form); b*u via per-thread 4-j quads:
// lane-varying operand read as one ds_read_b128 (index j0-o+r into r-shifted
// arrays, identical address x for all 4 forms), uniform operand from packed
// float4 table up[o>>2] (flat float index == o).
// ---------------------------------------------------------------------------
__global__ __launch_bounds__(256) void build_kernel(
    const float* __restrict__ er, const float* __restrict__ ed,
    const float* __restrict__ dr, const float* __restrict__ dd,
    const float* __restrict__ ab, const float* __restrict__ Tpref,
    bf16* __restrict__ Lh, bf16* __restrict__ Ll) {
  __shared__ __align__(16) float arr4[4][520];
  __shared__ __align__(16) float4 up[132];
  __shared__ float pa[512], parev[512], pd[512], pdrev[512], sdl[512];

  const int i = blockIdx.x;
  const int mat = blockIdx.y;
  const float* u = (mat < 4) ? (er + mat * H) : (dr + (mat - 4) * H);
  const float* d = (mat < 4) ? (ed + mat * H) : (dd + (mat - 4) * H);
  const float* a = ab + mat * 1024;
  const float* b = a + H;
  const float* tp = Tpref + mat * 2048;
  const int t = threadIdx.x;

  for (int m = t; m < 520; m += 256) {
    arr4[0][m] = (m < 512) ? u[m] : 0.f;                  // su[m]
    arr4[1][m] = (m >= 1 && m <= 512) ? b[m - 1] : 0.f;   // sb[m-1]
    arr4[2][m] = (m >= 2 && m <= 513) ? u[513 - m] : 0.f; // su_rev[m-2]
    arr4[3][m] = (m >= 3 && m <= 514) ? b[514 - m] : 0.f; // sb_rev[m-3]
  }
  for (int m = t; m < 512; m += 256) {
    pa[m] = tp[m];
    parev[m] = tp[512 + m];
    pd[m] = tp[1024 + m];
    pdrev[m] = tp[1536 + m];
    sdl[m] = d[m];
  }
  if (t < 132) {
    const int k4 = 4 * t;
    float4 v;
    int p0 = i - k4;
    v.x = (p0 >= 0 && p0 < 512) ? b[p0] : 0.f;            // r=0: b[i-o]
    int p1 = i - k4 - 1;
    v.y = (p1 >= 0 && p1 < 512) ? u[511 - p1] : 0.f;      // r=1: u[511-(i-o)]
    int p2 = i - k4 - 2;
    v.z = (p2 >= 0 && p2 < 512) ? b[511 - p2] : 0.f;      // r=2: b[511-(i-o)]
    int p3 = i - k4 - 3;
    v.w = (p3 >= 0 && p3 < 512) ? u[p3] : 0.f;            // r=3: u[i-o]
    up[t] = v;
  }
  __syncthreads();

  const float* upf = (const float*)up;
  const int j0 = t * 4;

  int lo_[4], hi_[4];
#pragma unroll
  for (int c = 0; c < 4; ++c) {
    const int jc = j0 + c;
    lo_[c] = max(0, max(i, jc) - 511);
    hi_[c] = min(512, min(i, jc));
  }
  const int CL = lo_[3];  // lo_c is nondecreasing in c
  const int CH = hi_[0];  // hi_c is nondecreasing in c

  float acc[4] = {0.f, 0.f, 0.f, 0.f};

  // ---- a-parts, diagonal parts via prefix lookups, per c ----
#pragma unroll
  for (int c = 0; c < 4; ++c) {
    const int jc = j0 + c;
    const int lo = lo_[c], hi = hi_[c];
    if (lo > hi) continue;
    float v = 0.f;
    {  // form0: a[i-o], o==0 mod 4
      int o1 = lo + ((0 - lo) & 3), o2 = hi - ((hi - 0) & 3);
      if (o1 <= o2) { int mx = i - o1, mn = i - o2; v += pa[mx] - (mn >= 4 ? pa[mn - 4] : 0.f); }
    }
    {  // form1: a[jc-o], o==1 mod 4
      int o1 = lo + ((1 - lo) & 3), o2 = hi - ((hi - 1) & 3);
      if (o1 <= o2) { int mx = jc - o1, mn = jc - o2; v += pa[mx] - (mn >= 4 ? pa[mn - 4] : 0.f); }
    }
    {  // form2: a_rev[i-o], o==2 mod 4
      int o1 = lo + ((2 - lo) & 3), o2 = hi - ((hi - 2) & 3);
      if (o1 <= o2) { int mx = i - o1, mn = i - o2; v += parev[mx] - (mn >= 4 ? parev[mn - 4] : 0.f); }
    }
    {  // form3: a_rev[jc-o], o==3 mod 4
      int o1 = lo + ((3 - lo) & 3), o2 = hi - ((hi - 3) & 3);
      if (o1 <= o2) { int mx = jc - o1, mn = jc - o2; v += parev[mx] - (mn >= 4 ? parev[mn - 4] : 0.f); }
    }
    if (i == jc) {  // main-diagonal deltas (forms 0 and 2)
      {
        int o1 = lo + ((0 - lo) & 3), o2 = hi - ((hi - 0) & 3);
        if (o1 <= o2) { int mx = i - o1, mn = i - o2; v += pd[mx] - (mn >= 4 ? pd[mn - 4] : 0.f); }
      }
      {
        int o1 = lo + ((2 - lo) & 3), o2 = hi - ((hi - 2) & 3);
        if (o1 <= o2) { int mx = i - o1, mn = i - o2; v += pdrev[mx] - (mn >= 4 ? pdrev[mn - 4] : 0.f); }
      }
    }
    const int m2 = i + jc - 511;  // anti-diagonal deltas (forms 1 and 3)
    if (m2 >= 0 && !(m2 & 1)) {
      const int os = m2 >> 1;
      if (os >= lo && os <= hi) {
        const int r = os & 3;
        if (r == 1) v += sdl[jc - os];
        else if (r == 3) v += sdl[511 - (jc - os)];
      }
    }
    acc[c] = v;
  }

  // ---- b*u parts ----
  if (CL > CH) {
    // degenerate corner: per-c scalar over [lo_c, hi_c] (<= ~6 iters)
#pragma unroll
    for (int c = 0; c < 4; ++c) {
      const int jc = j0 + c;
      for (int o = lo_[c]; o <= hi_[c]; ++o) {
        const int r = o & 3;
        acc[c] += upf[o] * arr4[r][jc - o + r];
      }
    }
  } else {
    // per-c edges outside the common range [CL, CH] (<=3 each side)
#pragma unroll
    for (int c = 0; c < 4; ++c) {
      const int jc = j0 + c;
      const int he = min(hi_[c], CL - 1);
      for (int o = lo_[c]; o <= he; ++o) {
        const int r = o & 3;
        acc[c] += upf[o] * arr4[r][jc - o + r];
      }
      const int ls = max(lo_[c], CH + 1);
      for (int o = ls; o <= hi_[c]; ++o) {
        const int r = o & 3;
        acc[c] += upf[o] * arr4[r][jc - o + r];
      }
    }
    // head singles to 4-alignment (common validity for all c)
    const int QL = (CL + 3) & ~3;
    for (int o = CL; o < QL && o <= CH; ++o) {
      const int r = o & 3;
      const float uvv = upf[o];
      const float4 wv = *(const float4*)&arr4[r][j0 - o + r];  // (j0-o+r)%4==0
      acc[0] += uvv * wv.x; acc[1] += uvv * wv.y;
      acc[2] += uvv * wv.z; acc[3] += uvv * wv.w;
    }
    // main quad loop
    int ob = QL;
    for (; ob + 3 <= CH; ob += 4) {
      const float4 uv = up[ob >> 2];
      const int x = j0 - ob;  // %4 == 0
      const float4 w0 = *(const float4*)&arr4[0][x];
      const float4 w1 = *(const float4*)&arr4[1][x];
      const float4 w2 = *(const float4*)&arr4[2][x];
      const float4 w3 = *(const float4*)&arr4[3][x];
      acc[0] += uv.x * w0.x + uv.y * w1.x + uv.z * w2.x + uv.w * w3.x;
      acc[1] += uv.x * w0.y + uv.y * w1.y + uv.z * w2.y + uv.w * w3.y;
      acc[2] += uv.x * w0.z + uv.y * w1.z + uv.z * w2.z + uv.w * w3.z;
      acc[3] += uv.x * w0.w + uv.y * w1.w + uv.z * w2.w + uv.w * w3.w;
    }
    // tail singles
    for (int o = ob; o <= CH; ++o) {
      const int r = o & 3;
      const float uvv = upf[o];
      const float4 wv = *(const float4*)&arr4[r][j0 - o + r];
      acc[0] += uvv * wv.x; acc[1] += uvv * wv.y;
      acc[2] += uvv * wv.z; acc[3] += uvv * wv.w;
    }
  }

  // ---- split write: 4 consecutive j's, 8B per thread, coalesced ----
  const size_t off = ((size_t)mat << 20) + ((size_t)i << 10) + (size_t)j0;
  union { bf16 v[4]; ushort4 s; } Hu, Lu;
#pragma unroll
  for (int c = 0; c < 4; ++c) {
    const bf16 hb = __float2bfloat16(acc[c]);
    Hu.v[c] = hb;
    Lu.v[c] = __float2bfloat16(acc[c] - __bfloat162float(hb));
  }
  *(ushort4*)(Lh + off) = Hu.s;
  *(ushort4*)(Ll + off) = Lu.s;
}

// ---------------------------------------------------------------------------
// split fp32 -> (hi, lo) bf16
// ---------------------------------------------------------------------------
__global__ void split_kernel(const float* __restrict__ x, bf16* __restrict__ h,
                             bf16* __restrict__ l) {
  const int n4 = BATCH * NFEAT / 4;
  int idx = blockIdx.x * blockDim.x + threadIdx.x;
  int stride = gridDim.x * blockDim.x;
  for (int i = idx; i < n4; i += stride) {
    float4 v = ((const float4*)x)[i];
    float vv[4] = {v.x, v.y, v.z, v.w};
    union { bf16 b[4]; short4 s; } Hu, Lu;
#pragma unroll
    for (int c = 0; c < 4; ++c) {
      bf16 hb = __float2bfloat16(vv[c]);
      Hu.b[c] = hb;
      Lu.b[c] = __float2bfloat16(vv[c] - __bfloat162float(hb));
    }
    ((short4*)h)[i] = Hu.s;
    ((short4*)l)[i] = Lu.s;
  }
}

// ---------------------------------------------------------------------------
// split-bf16 GEMM:  Y[r][c] = sum_k S[r][k] * L[c][k]   (i.e. Y = S @ L^T)
// acc += Ah*Bh + Ah*Bl + Al*Bh  (fp32 accum); 128x128 tile, BK=32, 4 waves.
// MODE bit0: write fp32 Yf; bit1: write split (Yh, Yl)
// ---------------------------------------------------------------------------
template <int MODE>
__global__ __launch_bounds__(256) void gemm3_kernel(
    const bf16* __restrict__ Ah, const bf16* __restrict__ Al,
    const bf16* __restrict__ Bh, const bf16* __restrict__ Bl,
    float* __restrict__ Yf, bf16* __restrict__ Yh, bf16* __restrict__ Yl) {
  __shared__ __align__(16) bf16 sAh[128 * 32];
  __shared__ __align__(16) bf16 sAl[128 * 32];
  __shared__ __align__(16) bf16 sBh[128 * 32];
  __shared__ __align__(16) bf16 sBl[128 * 32];

  const int tid = threadIdx.x;
  const int lane = tid & 63;
  const int wave = tid >> 6;
  const int wr = wave >> 1;
  const int wc = wave & 1;
  const int row0 = blockIdx.x * 128;
  const int col0 = blockIdx.y * 128;

  const int srow = tid >> 2;
  const int kq = tid & 3;
  const size_t aoff0 = (size_t)(row0 + srow) * NFEAT + (size_t)kq * 8;
  const size_t aoff1 = aoff0 + (size_t)64 * NFEAT;
  const size_t boff0 = (size_t)(col0 + srow) * NFEAT + (size_t)kq * 8;
  const size_t boff1 = boff0 + (size_t)64 * NFEAT;
  const int ldst = tid * 8;

  f32x4 acc[4][4] = {};

  for (int k0 = 0; k0 < NFEAT; k0 += 32) {
    gload16(sAh + ldst,        Ah + aoff0 + k0);
    gload16(sAh + 2048 + ldst, Ah + aoff1 + k0);
    gload16(sAl + ldst,        Al + aoff0 + k0);
    gload16(sAl + 2048 + ldst, Al + aoff1 + k0);
    gload16(sBh + ldst,        Bh + boff0 + k0);
    gload16(sBh + 2048 + ldst, Bh + boff1 + k0);
    gload16(sBl + ldst,        Bl + boff0 + k0);
    gload16(sBl + 2048 + ldst, Bl + boff1 + k0);
    __syncthreads();

    const int r16 = lane & 15;
    const int kg = (lane >> 4) * 8;
    bf16x8 fah[4], fal[4], fbh[4], fbl[4];
#pragma unroll
    for (int m = 0; m < 4; ++m) {
      int ra = (wr * 64 + m * 16 + r16) * 32 + kg;
      fah[m] = *(const bf16x8*)(sAh + ra);
      fal[m] = *(const bf16x8*)(sAl + ra);
      int rb = (wc * 64 + m * 16 + r16) * 32 + kg;
      fbh[m] = *(const bf16x8*)(sBh + rb);
      fbl[m] = *(const bf16x8*)(sBl + rb);
    }
#pragma unroll
    for (int m = 0; m < 4; ++m)
#pragma unroll
      for (int n = 0; n < 4; ++n) {
        acc[m][n] = __builtin_amdgcn_mfma_f32_16x16x32_bf16(fah[m], fbh[n], acc[m][n], 0, 0, 0);
        acc[m][n] = __builtin_amdgcn_mfma_f32_16x16x32_bf16(fah[m], fbl[n], acc[m][n], 0, 0, 0);
        acc[m][n] = __builtin_amdgcn_mfma_f32_16x16x32_bf16(fal[m], fbh[n], acc[m][n], 0, 0, 0);
      }
    __syncthreads();
  }

  const int orow = wr * 64 + ((lane >> 4) << 2);
  const int ocol = wc * 64 + (lane & 15);
#pragma unroll
  for (int m = 0; m < 4; ++m)
#pragma unroll
    for (int n = 0; n < 4; ++n)
#pragma unroll
      for (int r = 0; r < 4; ++r) {
        const int grow = row0 + orow + m * 16 + r;
        const int gcol = col0 + ocol + n * 16;
        const size_t off = (size_t)grow * NFEAT + (size_t)gcol;
        const float v = acc[m][n][r];
        if (MODE & 1) Yf[off] = v;
        if (MODE & 2) {
          bf16 hb = __float2bfloat16(v);
          Yh[off] = hb;
          Yl[off] = __float2bfloat16(v - __bfloat162float(hb));
        }
      }
}

// ---------------------------------------------------------------------------
// launch
// ---------------------------------------------------------------------------
extern "C" void kernel_launch(void* const* d_in, const int* in_sizes, int n_in,
                              void* d_out, int out_size, void* d_ws, size_t ws_size,
                              hipStream_t stream) {
  (void)in_sizes; (void)n_in; (void)out_size; (void)ws_size;
  const float* x  = (const float*)d_in[0];
  const float* er = (const float*)d_in[1];
  const float* ed = (const float*)d_in[2];
  const float* dr = (const float*)d_in[3];
  const float* dd = (const float*)d_in[4];

  float* O0 = (float*)d_out;                       // bottleneck (fp32, 64 MB)
  float* O1 = O0 + (size_t)BATCH * NFEAT;          // out (fp32, 64 MB)

  // d_ws layout: Lh (16MB) | Ll (16MB) | ab (32KB) | Ph (32MB) | Pl (32MB)
  bf16* Lh = (bf16*)d_ws;
  bf16* Ll = Lh + ((size_t)8 << 20);
  float* ab = (float*)(Ll + ((size_t)8 << 20));
  bf16* Ph = (bf16*)(ab + 8 * 1024);
  bf16* Pl = Ph + (size_t)BATCH * NFEAT;
  // Tpref (64KB) lives at the start of d_out: consumed by build_kernel,
  // overwritten later by the layer-4 GEMM epilogue (stream-ordered).
  float* Tpref = O0;
  // d_out second half doubles as bf16 hi/lo ping buffer until layer 8 overwrites it
  bf16* Qh = (bf16*)O1;
  bf16* Ql = Qh + (size_t)BATCH * NFEAT;

  prep_kernel<<<8, 64, 0, stream>>>(er, ed, dr, dd, ab);
  prep2_kernel<<<8, 256, 0, stream>>>(er, ed, dr, dd, ab, Tpref);
  build_kernel<<<dim3(1024, 8), 256, 0, stream>>>(er, ed, dr, dd, ab, Tpref, Lh, Ll);
  split_kernel<<<4096, 256, 0, stream>>>(x, Qh, Ql);

  const dim3 g(128, 8);
  const size_t LM = (size_t)1 << 20;
  // encoder
  gemm3_kernel<2><<<g, 256, 0, stream>>>(Qh, Ql, Lh + 0 * LM, Ll + 0 * LM, nullptr, Ph, Pl);
  gemm3_kernel<2><<<g, 256, 0, stream>>>(Ph, Pl, Lh + 1 * LM, Ll + 1 * LM, nullptr, Qh, Ql);
  gemm3_kernel<2><<<g, 256, 0, stream>>>(Qh, Ql, Lh + 2 * LM, Ll + 2 * LM, nullptr, Ph, Pl);
  gemm3_kernel<3><<<g, 256, 0, stream>>>(Ph, Pl, Lh + 3 * LM, Ll + 3 * LM, O0, Qh, Ql);
  // decoder
  gemm3_kernel<2><<<g, 256, 0, stream>>>(Qh, Ql, Lh + 4 * LM, Ll + 4 * LM, nullptr, Ph, Pl);
  gemm3_kernel<2><<<g, 256, 0, stream>>>(Ph, Pl, Lh + 5 * LM, Ll + 5 * LM, nullptr, Qh, Ql);
  gemm3_kernel<2><<<g, 256, 0, stream>>>(Qh, Ql, Lh + 6 * LM, Ll + 6 * LM, nullptr, Ph, Pl);
  gemm3_kernel<1><<<g, 256, 0, stream>>>(Ph, Pl, Lh + 7 * LM, Ll + 7 * LM, O1, nullptr, nullptr);
}

// Round 4
// 921.970 us; speedup vs baseline: 1.9226x; 1.0639x over previous
//
#include <hip/hip_runtime.h>
#include <hip/hip_bf16.h>
#include <cstdint>
#include <cstddef>

#define H 512
#define NFEAT 1024
#define BATCH 16384

using bf16 = __hip_bfloat16;
using bf16x8 = __attribute__((ext_vector_type(8))) __bf16;
using f32x4 = __attribute__((ext_vector_type(4))) float;
using f32x16 = __attribute__((ext_vector_type(16))) float;

// ---------------------------------------------------------------------------
// async global -> LDS, 16 bytes per lane
// ---------------------------------------------------------------------------
__device__ __forceinline__ void gload16(void* lds, const void* g) {
  __builtin_amdgcn_global_load_lds(
      (__attribute__((address_space(1))) void*)g,
      (__attribute__((address_space(3))) void*)lds,
      16, 0, 0);
}

// ---------------------------------------------------------------------------
// prep: per matrix, compute a[], b[] for core = diag(d) + a*1^T + b*u^T
// Closed-form Cayley (rank-2 Woodbury), verified R0-R2.
// ---------------------------------------------------------------------------
__global__ void prep_kernel(const float* __restrict__ er, const float* __restrict__ ed,
                            const float* __restrict__ dr, const float* __restrict__ dd,
                            float* __restrict__ ab) {
  const int mat = blockIdx.x;          // 0..7
  const int lane = threadIdx.x;        // 0..63
  const float* u = (mat < 4) ? (er + mat * H) : (dr + (mat - 4) * H);
  const float* d = (mat < 4) ? (ed + mat * H) : (dd + (mat - 4) * H);

  double s = 0.0, q = 0.0;
  for (int k = 0; k < 8; ++k) {
    double v = (double)u[lane + 64 * k];
    s += v;
    q += v * v;
  }
  for (int off = 32; off; off >>= 1) {
    s += __shfl_down(s, off);
    q += __shfl_down(q, off);
  }
  s = __shfl(s, 0);
  q = __shfl(q, 0);

  const double det = 1.0 - s * s + (double)H * q;
  const double cuv = 2.0 * (1.0 + s) / det;
  const double cuu = -2.0 * (double)H / det;
  const double cvv = -2.0 * q / det;
  const double cvu = -2.0 * (1.0 - s) / det;

  float* a = ab + mat * 1024;
  float* b = a + H;
  for (int k = 0; k < 8; ++k) {
    int idx = lane + 64 * k;
    double ui = (double)u[idx], di = (double)d[idx];
    a[idx] = (float)(di * (cuv * ui + cvv));
    b[idx] = (float)(di * (cuu * ui + cvu));
  }
}

// ---------------------------------------------------------------------------
// prep2: stride-4-residue inclusive prefix tables over a, a_rev, d, d_rev.
// ---------------------------------------------------------------------------
__global__ __launch_bounds__(256) void prep2_kernel(
    const float* __restrict__ er, const float* __restrict__ ed,
    const float* __restrict__ dr, const float* __restrict__ dd,
    const float* __restrict__ ab, float* __restrict__ Tpref) {
  __shared__ float buf[4][512];
  __shared__ float tmp[4][512];
  const int mat = blockIdx.x;
  const float* d = (mat < 4) ? (ed + mat * H) : (dd + (mat - 4) * H);
  const float* a = ab + mat * 1024;
  const int t = threadIdx.x;
  for (int m = t; m < 512; m += 256) {
    buf[0][m] = a[m];
    buf[1][m] = a[511 - m];
    buf[2][m] = d[m];
    buf[3][m] = d[511 - m];
  }
  __syncthreads();
  for (int s = 4; s <= 256; s <<= 1) {
    for (int m = t; m < 512; m += 256)
#pragma unroll
      for (int q = 0; q < 4; ++q) tmp[q][m] = (m >= s) ? buf[q][m - s] : 0.f;
    __syncthreads();
    for (int m = t; m < 512; m += 256)
#pragma unroll
      for (int q = 0; q < 4; ++q) buf[q][m] += tmp[q][m];
    __syncthreads();
  }
  float* tp = Tpref + mat * 2048;
  for (int m = t; m < 512; m += 256) {
    tp[m] = buf[0][m];
    tp[512 + m] = buf[1][m];
    tp[1024 + m] = buf[2][m];
    tp[1536 + m] = buf[3][m];
  }
}

// ---------------------------------------------------------------------------
// build v3 (unchanged from R2): prefix tables + quad b*u loop.
// ---------------------------------------------------------------------------
__global__ __launch_bounds__(256) void build_kernel(
    const float* __restrict__ er, const float* __restrict__ ed,
    const float* __restrict__ dr, const float* __restrict__ dd,
    const float* __restrict__ ab, const float* __restrict__ Tpref,
    bf16* __restrict__ Lh, bf16* __restrict__ Ll) {
  __shared__ __align__(16) float arr4[4][520];
  __shared__ __align__(16) float4 up[132];
  __shared__ float pa[512], parev[512], pd[512], pdrev[512], sdl[512];

  const int i = blockIdx.x;
  const int mat = blockIdx.y;
  const float* u = (mat < 4) ? (er + mat * H) : (dr + (mat - 4) * H);
  const float* d = (mat < 4) ? (ed + mat * H) : (dd + (mat - 4) * H);
  const float* a = ab + mat * 1024;
  const float* b = a + H;
  const float* tp = Tpref + mat * 2048;
  const int t = threadIdx.x;

  for (int m = t; m < 520; m += 256) {
    arr4[0][m] = (m < 512) ? u[m] : 0.f;
    arr4[1][m] = (m >= 1 && m <= 512) ? b[m - 1] : 0.f;
    arr4[2][m] = (m >= 2 && m <= 513) ? u[513 - m] : 0.f;
    arr4[3][m] = (m >= 3 && m <= 514) ? b[514 - m] : 0.f;
  }
  for (int m = t; m < 512; m += 256) {
    pa[m] = tp[m];
    parev[m] = tp[512 + m];
    pd[m] = tp[1024 + m];
    pdrev[m] = tp[1536 + m];
    sdl[m] = d[m];
  }
  if (t < 132) {
    const int k4 = 4 * t;
    float4 v;
    int p0 = i - k4;
    v.x = (p0 >= 0 && p0 < 512) ? b[p0] : 0.f;
    int p1 = i - k4 - 1;
    v.y = (p1 >= 0 && p1 < 512) ? u[511 - p1] : 0.f;
    int p2 = i - k4 - 2;
    v.z = (p2 >= 0 && p2 < 512) ? b[511 - p2] : 0.f;
    int p3 = i - k4 - 3;
    v.w = (p3 >= 0 && p3 < 512) ? u[p3] : 0.f;
    up[t] = v;
  }
  __syncthreads();

  const float* upf = (const float*)up;
  const int j0 = t * 4;

  int lo_[4], hi_[4];
#pragma unroll
  for (int c = 0; c < 4; ++c) {
    const int jc = j0 + c;
    lo_[c] = max(0, max(i, jc) - 511);
    hi_[c] = min(512, min(i, jc));
  }
  const int CL = lo_[3];
  const int CH = hi_[0];

  float acc[4] = {0.f, 0.f, 0.f, 0.f};

#pragma unroll
  for (int c = 0; c < 4; ++c) {
    const int jc = j0 + c;
    const int lo = lo_[c], hi = hi_[c];
    if (lo > hi) continue;
    float v = 0.f;
    {
      int o1 = lo + ((0 - lo) & 3), o2 = hi - ((hi - 0) & 3);
      if (o1 <= o2) { int mx = i - o1, mn = i - o2; v += pa[mx] - (mn >= 4 ? pa[mn - 4] : 0.f); }
    }
    {
      int o1 = lo + ((1 - lo) & 3), o2 = hi - ((hi - 1) & 3);
      if (o1 <= o2) { int mx = jc - o1, mn = jc - o2; v += pa[mx] - (mn >= 4 ? pa[mn - 4] : 0.f); }
    }
    {
      int o1 = lo + ((2 - lo) & 3), o2 = hi - ((hi - 2) & 3);
      if (o1 <= o2) { int mx = i - o1, mn = i - o2; v += parev[mx] - (mn >= 4 ? parev[mn - 4] : 0.f); }
    }
    {
      int o1 = lo + ((3 - lo) & 3), o2 = hi - ((hi - 3) & 3);
      if (o1 <= o2) { int mx = jc - o1, mn = jc - o2; v += parev[mx] - (mn >= 4 ? parev[mn - 4] : 0.f); }
    }
    if (i == jc) {
      {
        int o1 = lo + ((0 - lo) & 3), o2 = hi - ((hi - 0) & 3);
        if (o1 <= o2) { int mx = i - o1, mn = i - o2; v += pd[mx] - (mn >= 4 ? pd[mn - 4] : 0.f); }
      }
      {
        int o1 = lo + ((2 - lo) & 3), o2 = hi - ((hi - 2) & 3);
        if (o1 <= o2) { int mx = i - o1, mn = i - o2; v += pdrev[mx] - (mn >= 4 ? pdrev[mn - 4] : 0.f); }
      }
    }
    const int m2 = i + jc - 511;
    if (m2 >= 0 && !(m2 & 1)) {
      const int os = m2 >> 1;
      if (os >= lo && os <= hi) {
        const int r = os & 3;
        if (r == 1) v += sdl[jc - os];
        else if (r == 3) v += sdl[511 - (jc - os)];
      }
    }
    acc[c] = v;
  }

  if (CL > CH) {
#pragma unroll
    for (int c = 0; c < 4; ++c) {
      const int jc = j0 + c;
      for (int o = lo_[c]; o <= hi_[c]; ++o) {
        const int r = o & 3;
        acc[c] += upf[o] * arr4[r][jc - o + r];
      }
    }
  } else {
#pragma unroll
    for (int c = 0; c < 4; ++c) {
      const int jc = j0 + c;
      const int he = min(hi_[c], CL - 1);
      for (int o = lo_[c]; o <= he; ++o) {
        const int r = o & 3;
        acc[c] += upf[o] * arr4[r][jc - o + r];
      }
      const int ls = max(lo_[c], CH + 1);
      for (int o = ls; o <= hi_[c]; ++o) {
        const int r = o & 3;
        acc[c] += upf[o] * arr4[r][jc - o + r];
      }
    }
    const int QL = (CL + 3) & ~3;
    for (int o = CL; o < QL && o <= CH; ++o) {
      const int r = o & 3;
      const float uvv = upf[o];
      const float4 wv = *(const float4*)&arr4[r][j0 - o + r];
      acc[0] += uvv * wv.x; acc[1] += uvv * wv.y;
      acc[2] += uvv * wv.z; acc[3] += uvv * wv.w;
    }
    int ob = QL;
    for (; ob + 3 <= CH; ob += 4) {
      const float4 uv = up[ob >> 2];
      const int x = j0 - ob;
      const float4 w0 = *(const float4*)&arr4[0][x];
      const float4 w1 = *(const float4*)&arr4[1][x];
      const float4 w2 = *(const float4*)&arr4[2][x];
      const float4 w3 = *(const float4*)&arr4[3][x];
      acc[0] += uv.x * w0.x + uv.y * w1.x + uv.z * w2.x + uv.w * w3.x;
      acc[1] += uv.x * w0.y + uv.y * w1.y + uv.z * w2.y + uv.w * w3.y;
      acc[2] += uv.x * w0.z + uv.y * w1.z + uv.z * w2.z + uv.w * w3.z;
      acc[3] += uv.x * w0.w + uv.y * w1.w + uv.z * w2.w + uv.w * w3.w;
    }
    for (int o = ob; o <= CH; ++o) {
      const int r = o & 3;
      const float uvv = upf[o];
      const float4 wv = *(const float4*)&arr4[r][j0 - o + r];
      acc[0] += uvv * wv.x; acc[1] += uvv * wv.y;
      acc[2] += uvv * wv.z; acc[3] += uvv * wv.w;
    }
  }

  const size_t off = ((size_t)mat << 20) + ((size_t)i << 10) + (size_t)j0;
  union { bf16 v[4]; ushort4 s; } Hu, Lu;
#pragma unroll
  for (int c = 0; c < 4; ++c) {
    const bf16 hb = __float2bfloat16(acc[c]);
    Hu.v[c] = hb;
    Lu.v[c] = __float2bfloat16(acc[c] - __bfloat162float(hb));
  }
  *(ushort4*)(Lh + off) = Hu.s;
  *(ushort4*)(Ll + off) = Lu.s;
}

// ---------------------------------------------------------------------------
// split fp32 -> (hi, lo) bf16
// ---------------------------------------------------------------------------
__global__ void split_kernel(const float* __restrict__ x, bf16* __restrict__ h,
                             bf16* __restrict__ l) {
  const int n4 = BATCH * NFEAT / 4;
  int idx = blockIdx.x * blockDim.x + threadIdx.x;
  int stride = gridDim.x * blockDim.x;
  for (int i = idx; i < n4; i += stride) {
    float4 v = ((const float4*)x)[i];
    float vv[4] = {v.x, v.y, v.z, v.w};
    union { bf16 b[4]; short4 s; } Hu, Lu;
#pragma unroll
    for (int c = 0; c < 4; ++c) {
      bf16 hb = __float2bfloat16(vv[c]);
      Hu.b[c] = hb;
      Lu.b[c] = __float2bfloat16(vv[c] - __bfloat162float(hb));
    }
    ((short4*)h)[i] = Hu.s;
    ((short4*)l)[i] = Lu.s;
  }
}

// ---------------------------------------------------------------------------
// split-bf16 GEMM v2:  Y[r][c] = sum_k S[r][k] * L[c][k]  (Y = S @ L^T)
// acc += Ah*Bh + Ah*Bl + Al*Bh (fp32 accum).
// 128x128 tile, BK=64, 4 waves (2x2, 64x64 each), mfma_f32_32x32x16_bf16.
// LDS tiles [128][64] bf16 (128-B rows) with XOR swizzle
//   phys_byte = byte ^ ((row&7)<<4)   (involution; key bits 7-9 disjoint
//   from target bits 4-6) -> ds_read_b128 granules uniform over 8 slots.
// Staging: global_load_lds linear dest + inverse-swizzled per-thread source.
// MODE bit0: write fp32 Yf; bit1: write split (Yh, Yl)
// ---------------------------------------------------------------------------
template <int MODE>
__global__ __launch_bounds__(256) void gemm3_kernel(
    const bf16* __restrict__ Ah, const bf16* __restrict__ Al,
    const bf16* __restrict__ Bh, const bf16* __restrict__ Bl,
    float* __restrict__ Yf, bf16* __restrict__ Yh, bf16* __restrict__ Yl) {
  __shared__ __align__(16) bf16 smem[4 * 8192];  // Ah | Al | Bh | Bl, 16KB each
  bf16* sAh = smem;
  bf16* sAl = smem + 8192;
  bf16* sBh = smem + 16384;
  bf16* sBl = smem + 24576;

  const int tid = threadIdx.x;
  const int lane = tid & 63;
  const int wave = tid >> 6;
  const int wr = wave >> 1;
  const int wc = wave & 1;
  const int row0 = blockIdx.x * 128;  // batch rows (fast-varying: B panels L2-hot)
  const int col0 = blockIdx.y * 128;  // output features

  // staging: thread's 16-B dest D = q*4096 + tid*16 (bytes, linear).
  // logical row = q*32 + (tid>>3); logical colByte = (tid*16 ^ ((tid>>3&7)<<4)) & 127
  const int srow = tid >> 3;                                              // 0..31
  const int sce = (((tid * 16) ^ (((tid >> 3) & 7) << 4)) & 127) >> 1;    // elem col
  const size_t abase = (size_t)(row0 + srow) * NFEAT + sce;
  const size_t bbase = (size_t)(col0 + srow) * NFEAT + sce;
  const int dst0 = tid * 8;  // element offset of dest within tile (q=0)

  f32x16 acc[2][2] = {};

  for (int kt = 0; kt < 16; ++kt) {
    const int k0 = kt * 64;
#pragma unroll
    for (int q = 0; q < 4; ++q) {
      const size_t ga = abase + (size_t)(32 * q) * NFEAT + k0;
      const size_t gb = bbase + (size_t)(32 * q) * NFEAT + k0;
      const int dq = q * 2048 + dst0;
      gload16(sAh + dq, Ah + ga);
      gload16(sAl + dq, Al + ga);
      gload16(sBh + dq, Bh + gb);
      gload16(sBl + dq, Bl + gb);
    }
    __syncthreads();

    const int l31 = lane & 31;
    const int kh16 = (lane >> 5) * 16;  // byte offset of k-half within 32-B ks block
#pragma unroll
    for (int ks = 0; ks < 4; ++ks) {
      bf16x8 fah[2], fal[2], fbh[2], fbl[2];
#pragma unroll
      for (int m = 0; m < 2; ++m) {
        const int arow = wr * 64 + m * 32 + l31;
        const int ab = (arow * 128 + ks * 32 + kh16) ^ ((arow & 7) << 4);
        fah[m] = *(const bf16x8*)((const char*)sAh + ab);
        fal[m] = *(const bf16x8*)((const char*)sAl + ab);
        const int brow = wc * 64 + m * 32 + l31;
        const int bb = (brow * 128 + ks * 32 + kh16) ^ ((brow & 7) << 4);
        fbh[m] = *(const bf16x8*)((const char*)sBh + bb);
        fbl[m] = *(const bf16x8*)((const char*)sBl + bb);
      }
#pragma unroll
      for (int m = 0; m < 2; ++m)
#pragma unroll
        for (int n = 0; n < 2; ++n) {
          acc[m][n] = __builtin_amdgcn_mfma_f32_32x32x16_bf16(fah[m], fbh[n], acc[m][n], 0, 0, 0);
          acc[m][n] = __builtin_amdgcn_mfma_f32_32x32x16_bf16(fah[m], fbl[n], acc[m][n], 0, 0, 0);
          acc[m][n] = __builtin_amdgcn_mfma_f32_32x32x16_bf16(fal[m], fbh[n], acc[m][n], 0, 0, 0);
        }
    }
    __syncthreads();
  }

  // epilogue: 32x32 C/D layout: col = lane&31, row = (reg&3)+8*(reg>>2)+4*(lane>>5)
  const int ocol0 = col0 + wc * 64 + (lane & 31);
  const int rb = (lane >> 5) << 2;  // 0 or 4
#pragma unroll
  for (int m = 0; m < 2; ++m)
#pragma unroll
    for (int n = 0; n < 2; ++n)
#pragma unroll
      for (int r = 0; r < 16; ++r) {
        const int grow = row0 + wr * 64 + m * 32 + (r & 3) + ((r >> 2) << 3) + rb;
        const int gcol = ocol0 + n * 32;
        const size_t off = (size_t)grow * NFEAT + (size_t)gcol;
        const float v = acc[m][n][r];
        if (MODE & 1) Yf[off] = v;
        if (MODE & 2) {
          bf16 hb = __float2bfloat16(v);
          Yh[off] = hb;
          Yl[off] = __float2bfloat16(v - __bfloat162float(hb));
        }
      }
}

// ---------------------------------------------------------------------------
// launch
// ---------------------------------------------------------------------------
extern "C" void kernel_launch(void* const* d_in, const int* in_sizes, int n_in,
                              void* d_out, int out_size, void* d_ws, size_t ws_size,
                              hipStream_t stream) {
  (void)in_sizes; (void)n_in; (void)out_size; (void)ws_size;
  const float* x  = (const float*)d_in[0];
  const float* er = (const float*)d_in[1];
  const float* ed = (const float*)d_in[2];
  const float* dr = (const float*)d_in[3];
  const float* dd = (const float*)d_in[4];

  float* O0 = (float*)d_out;                       // bottleneck (fp32, 64 MB)
  float* O1 = O0 + (size_t)BATCH * NFEAT;          // out (fp32, 64 MB)

  // d_ws layout: Lh (16MB) | Ll (16MB) | ab (32KB) | Ph (32MB) | Pl (32MB)
  bf16* Lh = (bf16*)d_ws;
  bf16* Ll = Lh + ((size_t)8 << 20);
  float* ab = (float*)(Ll + ((size_t)8 << 20));
  bf16* Ph = (bf16*)(ab + 8 * 1024);
  bf16* Pl = Ph + (size_t)BATCH * NFEAT;
  // Tpref (64KB) at start of d_out: consumed by build, overwritten by layer 4.
  float* Tpref = O0;
  // d_out second half doubles as bf16 hi/lo ping buffer until layer 8 overwrites it
  bf16* Qh = (bf16*)O1;
  bf16* Ql = Qh + (size_t)BATCH * NFEAT;

  prep_kernel<<<8, 64, 0, stream>>>(er, ed, dr, dd, ab);
  prep2_kernel<<<8, 256, 0, stream>>>(er, ed, dr, dd, ab, Tpref);
  build_kernel<<<dim3(1024, 8), 256, 0, stream>>>(er, ed, dr, dd, ab, Tpref, Lh, Ll);
  split_kernel<<<4096, 256, 0, stream>>>(x, Qh, Ql);

  const dim3 g(128, 8);
  const size_t LM = (size_t)1 << 20;
  // encoder
  gemm3_kernel<2><<<g, 256, 0, stream>>>(Qh, Ql, Lh + 0 * LM, Ll + 0 * LM, nullptr, Ph, Pl);
  gemm3_kernel<2><<<g, 256, 0, stream>>>(Ph, Pl, Lh + 1 * LM, Ll + 1 * LM, nullptr, Qh, Ql);
  gemm3_kernel<2><<<g, 256, 0, stream>>>(Qh, Ql, Lh + 2 * LM, Ll + 2 * LM, nullptr, Ph, Pl);
  gemm3_kernel<3><<<g, 256, 0, stream>>>(Ph, Pl, Lh + 3 * LM, Ll + 3 * LM, O0, Qh, Ql);
  // decoder
  gemm3_kernel<2><<<g, 256, 0, stream>>>(Qh, Ql, Lh + 4 * LM, Ll + 4 * LM, nullptr, Ph, Pl);
  gemm3_kernel<2><<<g, 256, 0, stream>>>(Ph, Pl, Lh + 5 * LM, Ll + 5 * LM, nullptr, Qh, Ql);
  gemm3_kernel<2><<<g, 256, 0, stream>>>(Qh, Ql, Lh + 6 * LM, Ll + 6 * LM, nullptr, Ph, Pl);
  gemm3_kernel<1><<<g, 256, 0, stream>>>(Ph, Pl, Lh + 7 * LM, Ll + 7 * LM, O1, nullptr, nullptr);
}